// Round 3
// baseline (172.827 us; speedup 1.0000x reference)
//
#include <hip/hip_runtime.h>

// SmoothnessLoss: error = sum_{c,h,w} x*(1 - cnt(h,w)*w) / (H*W)
// cnt(h,w) = nh*nw - 1, nh = 3-(h==0)-(h==H-1), nw = 3-(w==0)-(w==W-1).
// Derivation: summing the 8-neighbor gather over all pixels counts each
// wx[y,x'] once per valid neighbor slot == size of its own neighborhood.
//
// Single kernel: grid-stride-free exact partition (16 float4/thread),
// 4-deep load batching for MLP, per-block f64 partial, device-scope
// ticket so the last block does the final fixed-order reduction
// (saves the 2nd kernel launch + graph node gap).

#define HDIM 4096
#define WDIM 4096
#define NBLOCKS 2048
#define NTHREADS 256
#define N4 ((2 * HDIM * WDIM) / 4)
#define STRIDE (NBLOCKS * NTHREADS)
#define ITERS (N4 / STRIDE)   // = 16
#define BATCH 4

__global__ __launch_bounds__(NTHREADS) void smooth_kernel(
    const float4* __restrict__ x4,
    const float4* __restrict__ w4,
    double* __restrict__ partial,
    unsigned* __restrict__ counter,
    float* __restrict__ out)
{
    int tid = blockIdx.x * blockDim.x + threadIdx.x;

    double acc0 = 0.0, acc1 = 0.0, acc2 = 0.0, acc3 = 0.0;

    #pragma unroll
    for (int b = 0; b < ITERS; b += BATCH) {
        float4 xv[BATCH], wv[BATCH];
        #pragma unroll
        for (int k = 0; k < BATCH; ++k) {
            int i = tid + (b + k) * STRIDE;
            xv[k] = x4[i];
            wv[k] = w4[i];
        }
        #pragma unroll
        for (int k = 0; k < BATCH; ++k) {
            int i  = tid + (b + k) * STRIDE;
            int e  = i << 2;                 // flat element index of .x
            int ww = e & (WDIM - 1);         // column of .x
            int h  = (e >> 12) & (HDIM - 1); // row

            float nh  = 3.0f - (h == 0) - (h == HDIM - 1);
            float nw0 = (ww == 0)        ? 2.0f : 3.0f;
            float nw3 = (ww == WDIM - 4) ? 2.0f : 3.0f;
            float m1  = nh * 3.0f - 1.0f;

            acc0 += (double)(xv[k].x * (1.0f - (nh * nw0 - 1.0f) * wv[k].x));
            acc1 += (double)(xv[k].y * (1.0f - m1 * wv[k].y));
            acc2 += (double)(xv[k].z * (1.0f - m1 * wv[k].z));
            acc3 += (double)(xv[k].w * (1.0f - (nh * nw3 - 1.0f) * wv[k].w));
        }
    }

    double acc = (acc0 + acc1) + (acc2 + acc3);

    // wave(64) reduce
    for (int off = 32; off > 0; off >>= 1)
        acc += __shfl_down(acc, off, 64);

    __shared__ double lds[NTHREADS / 64];
    __shared__ bool is_last;
    int lane = threadIdx.x & 63;
    int wid  = threadIdx.x >> 6;
    if (lane == 0) lds[wid] = acc;
    __syncthreads();

    if (threadIdx.x == 0) {
        double s = (lds[0] + lds[1]) + (lds[2] + lds[3]);
        // device-scope release store of this block's partial
        __hip_atomic_store(&partial[blockIdx.x], s,
                           __ATOMIC_RELEASE, __HIP_MEMORY_SCOPE_AGENT);
        unsigned old = __hip_atomic_fetch_add(counter, 1u,
                           __ATOMIC_ACQ_REL, __HIP_MEMORY_SCOPE_AGENT);
        is_last = (old == NBLOCKS - 1);
    }
    __syncthreads();

    if (is_last) {
        // fixed-order final reduction: deterministic regardless of which
        // block executes it
        double a = 0.0;
        #pragma unroll
        for (int j = 0; j < NBLOCKS / NTHREADS; ++j)  // 8 per thread
            a += __hip_atomic_load(&partial[threadIdx.x + j * NTHREADS],
                                   __ATOMIC_ACQUIRE, __HIP_MEMORY_SCOPE_AGENT);
        for (int off = 32; off > 0; off >>= 1)
            a += __shfl_down(a, off, 64);
        if (lane == 0) lds[wid] = a;
        __syncthreads();
        if (threadIdx.x == 0) {
            double s = (lds[0] + lds[1]) + (lds[2] + lds[3]);
            out[0] = (float)(s / ((double)HDIM * (double)WDIM));
        }
    }
}

extern "C" void kernel_launch(void* const* d_in, const int* in_sizes, int n_in,
                              void* d_out, int out_size, void* d_ws, size_t ws_size,
                              hipStream_t stream) {
    const float4* x4 = (const float4*)d_in[0];
    const float4* w4 = (const float4*)d_in[1];
    float* out = (float*)d_out;

    double*   partial = (double*)d_ws;                       // 2048 * 8B
    unsigned* counter = (unsigned*)((char*)d_ws + NBLOCKS * sizeof(double));

    (void)in_sizes; (void)n_in; (void)out_size; (void)ws_size;

    // zero the ticket counter each call (graph-capturable memset node)
    hipMemsetAsync(counter, 0, sizeof(unsigned), stream);

    smooth_kernel<<<NBLOCKS, NTHREADS, 0, stream>>>(x4, w4, partial, counter, out);
}

// Round 4
// 47.273 us; speedup vs baseline: 3.6559x; 3.6559x over previous
//
#include <hip/hip_runtime.h>

// SmoothnessLoss: error = sum_{c,h,w} x*(1 - cnt(h,w)*w) / (H*W)
// cnt(h,w) = nh*nw - 1, nh = 3-(h==0)-(h==H-1), nw = 3-(w==0)-(w==W-1).
// Derivation: summing the 8-neighbor gather over all pixels counts each
// wx[y,x'] once per valid neighbor slot == size of its own neighborhood.
//
// R4 = R2 structure (two kernels, NO device-scope atomics/fences — R3's
// agent-scope acq/rel ticket cost ~125us in L2 cache-maintenance) plus
// R3's 4-deep load batching for memory-level parallelism.

#define HDIM 4096
#define WDIM 4096
#define NBLOCKS 2048
#define NTHREADS 256
#define N4 ((2 * HDIM * WDIM) / 4)
#define STRIDE (NBLOCKS * NTHREADS)
#define ITERS (N4 / STRIDE)   // = 16
#define BATCH 4

__global__ __launch_bounds__(NTHREADS) void smooth_partial_kernel(
    const float4* __restrict__ x4,
    const float4* __restrict__ w4,
    double* __restrict__ partial)
{
    int tid = blockIdx.x * blockDim.x + threadIdx.x;

    double acc0 = 0.0, acc1 = 0.0, acc2 = 0.0, acc3 = 0.0;

    #pragma unroll
    for (int b = 0; b < ITERS; b += BATCH) {
        float4 xv[BATCH], wv[BATCH];
        #pragma unroll
        for (int k = 0; k < BATCH; ++k) {
            int i = tid + (b + k) * STRIDE;
            xv[k] = x4[i];
            wv[k] = w4[i];
        }
        #pragma unroll
        for (int k = 0; k < BATCH; ++k) {
            int i  = tid + (b + k) * STRIDE;
            int e  = i << 2;                 // flat element index of .x
            int ww = e & (WDIM - 1);         // column of .x
            int h  = (e >> 12) & (HDIM - 1); // row

            float nh  = 3.0f - (h == 0) - (h == HDIM - 1);
            float nw0 = (ww == 0)        ? 2.0f : 3.0f;
            float nw3 = (ww == WDIM - 4) ? 2.0f : 3.0f;
            float m1  = nh * 3.0f - 1.0f;

            acc0 += (double)(xv[k].x * (1.0f - (nh * nw0 - 1.0f) * wv[k].x));
            acc1 += (double)(xv[k].y * (1.0f - m1 * wv[k].y));
            acc2 += (double)(xv[k].z * (1.0f - m1 * wv[k].z));
            acc3 += (double)(xv[k].w * (1.0f - (nh * nw3 - 1.0f) * wv[k].w));
        }
    }

    double acc = (acc0 + acc1) + (acc2 + acc3);

    // wave(64) reduce
    for (int off = 32; off > 0; off >>= 1)
        acc += __shfl_down(acc, off, 64);

    __shared__ double lds[NTHREADS / 64];
    int lane = threadIdx.x & 63;
    int wid  = threadIdx.x >> 6;
    if (lane == 0) lds[wid] = acc;
    __syncthreads();

    if (threadIdx.x == 0) {
        double s = (lds[0] + lds[1]) + (lds[2] + lds[3]);
        partial[blockIdx.x] = s;
    }
}

__global__ __launch_bounds__(NTHREADS) void smooth_final_kernel(
    const double* __restrict__ partial,
    float* __restrict__ out)
{
    double acc = 0.0;
    #pragma unroll
    for (int j = 0; j < NBLOCKS / NTHREADS; ++j)   // 8 per thread
        acc += partial[threadIdx.x + j * NTHREADS];

    for (int off = 32; off > 0; off >>= 1)
        acc += __shfl_down(acc, off, 64);

    __shared__ double lds[NTHREADS / 64];
    int lane = threadIdx.x & 63;
    int wid  = threadIdx.x >> 6;
    if (lane == 0) lds[wid] = acc;
    __syncthreads();

    if (threadIdx.x == 0) {
        double s = (lds[0] + lds[1]) + (lds[2] + lds[3]);
        out[0] = (float)(s / ((double)HDIM * (double)WDIM));
    }
}

extern "C" void kernel_launch(void* const* d_in, const int* in_sizes, int n_in,
                              void* d_out, int out_size, void* d_ws, size_t ws_size,
                              hipStream_t stream) {
    const float4* x4 = (const float4*)d_in[0];
    const float4* w4 = (const float4*)d_in[1];
    float* out = (float*)d_out;
    double* partial = (double*)d_ws;   // NBLOCKS doubles = 16 KB

    (void)in_sizes; (void)n_in; (void)out_size; (void)ws_size;

    smooth_partial_kernel<<<NBLOCKS, NTHREADS, 0, stream>>>(x4, w4, partial);
    smooth_final_kernel<<<1, NTHREADS, 0, stream>>>(partial, out);
}